// Round 6
// baseline (4348.408 us; speedup 1.0000x reference)
//
#include <hip/hip_runtime.h>

// Farthest Point Sampling: B=16, N=65536, S=2048. Out: (B, S, 3) fp32.
//
// Round-9 = round-8 (coords-in-slot) DE-RISKED. r8's bench container died
// twice with no diagnostics; the only hang-capable novel construct was the
// asm poll LOOP (hard-coded v32-v40, hand exec-mask branching). Replaced by
// a branch-free one-shot 32-B sample in asm (virtual regs, "=&v") wrapped
// in the r1/r3-proven per-lane HIP do{}while. r7 proved sampling is
// RTT-capped (MSHR-coalesced), so a HIP loop around a one-shot sample
// loses nothing vs a pipelined asm loop.
//
// Design: round-3 backbone (16 slots/batch, t0 block-publish, 16 poller
// lanes, both HW barriers) + COORDS-IN-SLOT: each block publishes its
// candidate's (val,idx) AND (x,y,z) in one 32-byte slot, so detection and
// coord delivery are a single poll response -- the dependent winner-coord
// fetch (~1 L3/HBM RTT on the critical path, per r7's FETCH decomposition)
// is eliminated.
//
// MEASURED LESSONS (encoded):
//  - r4: agent/system stores write through to HBM (WRITE_SIZE = stores x
//    32B); peer L2 never sees them -> L3/HBM is the only cross-block
//    mailbox. Publish stores MUST carry sc0 sc1 (plain stores could sit in
//    the local XCD L2 and deadlock peers).
//  - r5: 64 slots / 8 lines / 64 pollers / 4 publishes regressed 2300cy.
//    This round isolates the line-count factor: 8 lines but 16 pollers and
//    1 publish. If it regresses, line-count is the poison.
//  - r6: LDS tag-spins are worse than __syncthreads. Keep HW barriers.
//  - r7: same-address polls are MSHR-coalesced (FETCH stayed flat at 4-deep
//    pipelining) -- sampling capped at 1/RTT. Don't pipeline polls.
//
// Slot layout (32 B, every u64 word carries a seq copy -> tear-proof):
//   w0 = val32<<32 | inv16<<16 | seq16   (key word; u64 max = argmax)
//   w1 = seq32<<32 | xbits
//   w2 = seq32<<32 | ybits
//   w3 = seq32<<32 | zbits
// Parity-slot staleness is exactly {fresh, want-2} (lockstep argument), so
// exact-match seq can never false-match, per-word; cross-word tearing is
// harmless because every word is independently seq-verified.
//
// Numerics identical to r1-r7 / numpy: no FMA, ((dx*dx+dy*dy)+dz*dz),
// fminf, global first-occurrence argmax. absmax must stay 0.0.

typedef unsigned long long u64;
typedef unsigned uint4v __attribute__((ext_vector_type(4)));

#define BATCHES 16
#define NPTS    65536
#define NSAMP   2048
#define PB      16                    // blocks per batch
#define TPB     256                   // threads per block
#define WPB     (TPB / 64)            // 4 waves per block
#define PPT     (NPTS / (PB * TPB))   // 16 points per thread

#define WS_BYTES (2 * BATCHES * PB * 32)  // 16 KiB slot space

// DPP ctrl: 0xB1 xor1, 0x4E xor2, 0x141 row_half_mirror, 0x140 row_mirror,
// 0x142 row_bcast15, 0x143 row_bcast31.
// bound_ctrl 0-fill is a safe identity for unsigned max.
template <int CTRL>
__device__ __forceinline__ u64 dppmax_u64(u64 x) {
  unsigned lo = (unsigned)x, hi = (unsigned)(x >> 32);
  unsigned plo = (unsigned)__builtin_amdgcn_update_dpp(0, (int)lo, CTRL, 0xF, 0xF, true);
  unsigned phi = (unsigned)__builtin_amdgcn_update_dpp(0, (int)hi, CTRL, 0xF, 0xF, true);
  u64 pv = ((u64)phi << 32) | plo;
  return pv > x ? pv : x;
}

__device__ __forceinline__ u64 bcast63_u64(u64 m) {
  unsigned lo = (unsigned)__builtin_amdgcn_readlane((int)(unsigned)m, 63);
  unsigned hi = (unsigned)__builtin_amdgcn_readlane((int)(unsigned)(m >> 32), 63);
  return ((u64)hi << 32) | lo;
}

// One-shot 32-B system-scope sample: two dwordx4 loads, one waitcnt.
// Virtual registers only ("=&v" early-clobber); no branches; hang-safe.
__device__ __forceinline__ void sample32(const u64* sp, uint4v& a, uint4v& b) {
  asm volatile(
      "global_load_dwordx4 %0, %2, off sc0 sc1\n\t"
      "global_load_dwordx4 %1, %2, off offset:16 sc0 sc1\n\t"
      "s_waitcnt vmcnt(0)"
      : "=&v"(a), "=&v"(b)
      : "v"(sp)
      : "memory");
}

__global__ __launch_bounds__(TPB) void fps_kernel(
    const float* __restrict__ coords,
    float* __restrict__ out,
    u64* __restrict__ slots) {
  const int blk  = blockIdx.x;
  const int b    = blk >> 4;    // batch
  const int r    = blk & 15;    // rank within batch
  const int t    = threadIdx.x;
  const int lane = t & 63;
  const int wave = t >> 6;

  const float* __restrict__ cb = coords + (size_t)b * NPTS * 3;
  const int base = r * (TPB * PPT);

  // Register-resident points + closest-distance array.
  float px[PPT], py[PPT], pz[PPT], cl[PPT];
#pragma unroll
  for (int k = 0; k < PPT; ++k) {
    int idx = base + k * TPB + t;
    px[k] = cb[3 * idx + 0];
    py[k] = cb[3 * idx + 1];
    pz[k] = cb[3 * idx + 2];
    cl[k] = __builtin_inff();
  }

  __shared__ u64 s_pub[WPB][4];   // per-wave winner: 4 fully-formed slot words
  __shared__ float s_x, s_y, s_z;

  // Initial selected point: index 0 (matches reference).
  float sx = cb[0], sy = cb[1], sz = cb[2];

  for (int it = 0; it < NSAMP; ++it) {
    // --- distance update + per-thread argmax (ascending k => first occ.);
    // track best coords in registers so the winner needs no memory fetch ---
    float bestv = -1.0f;
    int bestk = 0;
    float bx = 0.0f, by = 0.0f, bz = 0.0f;
#pragma unroll
    for (int k = 0; k < PPT; ++k) {
      float dx = __fsub_rn(sx, px[k]);
      float dy = __fsub_rn(sy, py[k]);
      float dz = __fsub_rn(sz, pz[k]);
      float d  = __fadd_rn(__fadd_rn(__fmul_rn(dx, dx), __fmul_rn(dy, dy)),
                           __fmul_rn(dz, dz));
      float c  = fminf(cl[k], d);
      cl[k] = c;
      if (c > bestv) { bestv = c; bestk = k; bx = px[k]; by = py[k]; bz = pz[k]; }
    }
    const int bestidx = base + bestk * TPB + t;

    const int p = (it + 1) & 1;            // parity double-buffer
    const unsigned want32 = (unsigned)(it + 1);
    u64* bs = slots + (size_t)(p * BATCHES + b) * PB * 4;  // 4 u64s per slot

    // --- fused wave reduce: ONE 6-stage u64 DPP chain (bit-exact, r5-r7) ---
    const u64 mykey = ((u64)__float_as_uint(bestv) << 32) |
                      ((u64)(unsigned)(65535 - bestidx) << 16);
    u64 wk = mykey;
    wk = dppmax_u64<0xB1>(wk);
    wk = dppmax_u64<0x4E>(wk);
    wk = dppmax_u64<0x141>(wk);
    wk = dppmax_u64<0x140>(wk);
    wk = dppmax_u64<0x142>(wk);
    wk = dppmax_u64<0x143>(wk);
    const u64 wmax = bcast63_u64(wk);

    // Unique wave-winner lane (per-lane keys distinct: distinct bestidx)
    // deposits its fully-formed slot words (coords from registers).
    if (mykey == wmax) {
      s_pub[wave][0] = mykey | (u64)want32;
      s_pub[wave][1] = ((u64)want32 << 32) | (u64)__float_as_uint(bx);
      s_pub[wave][2] = ((u64)want32 << 32) | (u64)__float_as_uint(by);
      s_pub[wave][3] = ((u64)want32 << 32) | (u64)__float_as_uint(bz);
    }
    __syncthreads();  // barrier #1 (HW barrier: r6 proved spins are worse)

    // --- t0: pick argmax wave, publish 32-B slot (two system stores) ---
    if (t == 0) {
      u64 kb = s_pub[0][0];
      int wb = 0;
#pragma unroll
      for (int w = 1; w < WPB; ++w) {
        u64 o = s_pub[w][0];
        if (o > kb) { kb = o; wb = w; }
      }
      u64 a1 = s_pub[wb][1], a2 = s_pub[wb][2], a3 = s_pub[wb][3];
      uint4v q0 = { (unsigned)kb, (unsigned)(kb >> 32),
                    (unsigned)a1, (unsigned)(a1 >> 32) };
      uint4v q1 = { (unsigned)a2, (unsigned)(a2 >> 32),
                    (unsigned)a3, (unsigned)(a3 >> 32) };
      const u64* sp = bs + r * 4;
      asm volatile(
          "global_store_dwordx4 %0, %1, off sc0 sc1\n\t"
          "global_store_dwordx4 %0, %2, off offset:16 sc0 sc1"
          :: "v"(sp), "v"(q0), "v"(q1)
          : "memory");
    }
    asm volatile("" ::: "memory");  // keep publish above the poll

    // --- wave 0, lanes 0-15: poll own slot; coords arrive WITH detection.
    // Per-lane divergent do{}while (r1/r3-proven); one-shot asm sample. ---
    if (wave == 0 && lane < PB) {
      const u64* sp = bs + lane * 4;
      uint4v qa, qb;
      do {
        sample32(sp, qa, qb);
      } while ((qa.x & 0xFFFFu) != want32 || qa.w != want32 ||
               qb.y != want32 || qb.w != want32);

      const u64 sv = ((u64)qa.y << 32) | qa.x;  // key word
      const float gx = __uint_as_float(qa.z);
      const float gy = __uint_as_float(qb.x);
      const float gz = __uint_as_float(qb.z);

      // 16-lane slot reduce: 4 DPP stages within the row (r1/r3-proven).
      u64 m = sv;
      m = dppmax_u64<0xB1>(m);
      m = dppmax_u64<0x4E>(m);
      m = dppmax_u64<0x141>(m);
      m = dppmax_u64<0x140>(m);

      // Winner lane unique (disjoint idx ranges -> unique inv_idx).
      if (sv == m) {
        s_x = gx; s_y = gy; s_z = gz;
        if (r == 0) {
          float* op = out + ((size_t)b * NSAMP + it) * 3;
          op[0] = gx; op[1] = gy; op[2] = gz;
        }
      }
    }
    __syncthreads();  // barrier #2
    sx = s_x; sy = s_y; sz = s_z;
  }
}

extern "C" void kernel_launch(void* const* d_in, const int* in_sizes, int n_in,
                              void* d_out, int out_size, void* d_ws,
                              size_t ws_size, hipStream_t stream) {
  const float* coords = (const float*)d_in[0];  // (16, 65536, 3) fp32
  // d_in[1] (features) unused by the reference output.
  float* out = (float*)d_out;                   // (16, 2048, 3) fp32
  u64* slots = (u64*)d_ws;                      // 16 KiB
  hipMemsetAsync(d_ws, 0, WS_BYTES, stream);    // seq tags start at 0 != 1
  fps_kernel<<<dim3(BATCHES * PB), dim3(TPB), 0, stream>>>(coords, out, slots);
}

// Round 7
// 2877.264 us; speedup vs baseline: 1.5113x; 1.5113x over previous
//
#include <hip/hip_runtime.h>

// Farthest Point Sampling: B=16, N=65536, S=2048. Out: (B, S, 3) fp32.
//
// Round-10 design: r3's measured-best backbone (16 slots / 2 lines per
// batch, t0 single publish, 16 poller lanes, both HW barriers) with the
// mailbox moved from L3 latency (~900cy) to XCD-shared-L2 latency (~200cy)
// via same-XCD placement + PLAIN write-back stores.
//
// MEASURED LESSONS (encoded):
//  - r4: AGENT/system stores are no-allocate WRITE-THROUGH (WRITE_SIZE =
//    stores x 32B, exactly); they do NOT update a stale line present in the
//    XCD L2 -> sc0 polls spun stale. The r10 fix is store-side: plain
//    (write-back) stores must update-or-allocate the shared L2 line; any
//    resting place of the data (L2 or L3) is covered by one of the two
//    poll flavors (sc0 / agent). r4's grid remap + XCC_ID vote machinery
//    itself ran correctly and fell back safely.
//  - r5/r9: mailbox lines per poll sample and publish stores per round are
//    the poison (8 lines: +2300cy; 2x stores + 8 lines: +800cy). Keep
//    16 slots x 8B = 2 lines, ONE store per block-round.
//  - r6: LDS tag-spins are worse than __syncthreads (+600cy). HW barriers.
//  - r7: same-address polls are MSHR-coalesced; sampling capped at 1/RTT.
//    No software poll pipelining. (At L2 RTT ~200cy the cap is 4.5x softer.)
//  - Fused u64 key chain (val<<32 | inv<<16 | seq) bit-exact: absmax 0.0
//    in r5, r6, r7, r9.
//
// Fast-mode safety: exact seq tags (stale = want-2 / launch ghosts != want)
// can never false-match; liveness holds because a plain store's data ends
// up either in the shared L2 (sc0 samples see it) or in L3/HBM (every 4th
// sample is agent-scope). Vote-fail mode is byte-for-byte the r3/r7 path
// (agent store + agent polls), proven at 3525us.
//
// Numerics identical to r1-r9 / numpy: no FMA, ((dx*dx+dy*dy)+dz*dz),
// fminf, global first-occurrence argmax. absmax must stay 0.0.

typedef unsigned long long u64;

#define BATCHES 16
#define NPTS    65536
#define NSAMP   2048
#define PB      16                    // blocks per batch
#define TPB     256                   // threads per block
#define WPB     (TPB / 64)            // 4 waves per block
#define PPT     (NPTS / (PB * TPB))   // 16 points per thread

#define WS_SLOTS_BYTES (2 * BATCHES * PB * 8)              // 4 KiB
#define WS_TOTAL_BYTES (WS_SLOTS_BYTES + BATCHES * PB * 4) // + 1 KiB vote tab

// DPP ctrl: 0xB1 xor1, 0x4E xor2, 0x141 row_half_mirror, 0x140 row_mirror,
// 0x142 row_bcast15, 0x143 row_bcast31.
// bound_ctrl 0-fill is a safe identity for unsigned max.
template <int CTRL>
__device__ __forceinline__ u64 dppmax_u64(u64 x) {
  unsigned lo = (unsigned)x, hi = (unsigned)(x >> 32);
  unsigned plo = (unsigned)__builtin_amdgcn_update_dpp(0, (int)lo, CTRL, 0xF, 0xF, true);
  unsigned phi = (unsigned)__builtin_amdgcn_update_dpp(0, (int)hi, CTRL, 0xF, 0xF, true);
  u64 pv = ((u64)phi << 32) | plo;
  return pv > x ? pv : x;
}

// sc0-only load: bypass L1, served by the XCD-shared L2 (~200cy on hit).
// One-shot, branch-free, virtual regs -- hang-safe (ran fine in r4).
__device__ __forceinline__ u64 ld_sc0(const u64* p) {
  u64 v;
  asm volatile("global_load_dwordx2 %0, %1, off sc0\n\ts_waitcnt vmcnt(0)"
               : "=v"(v)
               : "v"(p)
               : "memory");
  return v;
}

__device__ __forceinline__ u64 ld_agent(const u64* p) {
  return __hip_atomic_load(p, __ATOMIC_RELAXED, __HIP_MEMORY_SCOPE_AGENT);
}

// Plain write-back store: allocates/updates the shared-L2 line (fast mode).
__device__ __forceinline__ void st_plain(u64* p, u64 v) {
  asm volatile("global_store_dwordx2 %0, %1, off" :: "v"(p), "v"(v) : "memory");
}

__global__ __launch_bounds__(TPB) void fps_kernel(
    const float* __restrict__ coords,
    float* __restrict__ out,
    u64* __restrict__ slots,
    unsigned* __restrict__ xcdtab) {
  const int g = blockIdx.x;
  const int b = 2 * (g & 7) + ((g >> 3) & 1);  // batch (XCD-grouped remap)
  const int r = g >> 4;                        // rank within batch
  const int t = threadIdx.x;
  const int lane = t & 63;
  const int wave = t >> 6;

  const float* __restrict__ cb = coords + (size_t)b * NPTS * 3;
  const int base = r * (TPB * PPT);

  // Register-resident points + closest-distance array.
  float px[PPT], py[PPT], pz[PPT], cl[PPT];
#pragma unroll
  for (int k = 0; k < PPT; ++k) {
    int idx = base + k * TPB + t;
    px[k] = cb[3 * idx + 0];
    py[k] = cb[3 * idx + 1];
    pz[k] = cb[3 * idx + 2];
    cl[k] = __builtin_inff();
  }

  __shared__ u64 s_wred[WPB];
  __shared__ float s_x, s_y, s_z;

  // --- one-time same-XCD vote (agent scope; table zeroed by host memset;
  // machinery HW-proven in r4, incl. clean fallback) ---
  // HW_REG_XCC_ID: s_getreg imm 0x1814 (id=20, offset=0, width=4).
  unsigned xcc = (unsigned)__builtin_amdgcn_s_getreg(0x1814) & 0xF;
  if (t == 0)
    __hip_atomic_store(&xcdtab[b * PB + r], xcc + 1, __ATOMIC_RELAXED,
                       __HIP_MEMORY_SCOPE_AGENT);
  unsigned ve;
  do {
    ve = __hip_atomic_load(&xcdtab[b * PB + (lane & 15)], __ATOMIC_RELAXED,
                           __HIP_MEMORY_SCOPE_AGENT);
  } while (ve == 0);
  const bool use_l2 = __all((int)(ve == __shfl(ve, 0)));  // batch-uniform

  // Initial selected point: index 0 (matches reference).
  float sx = cb[0], sy = cb[1], sz = cb[2];

  for (int it = 0; it < NSAMP; ++it) {
    // --- distance update + per-thread argmax (ascending k => first occ.) ---
    float bestv = -1.0f;
    int bestk = 0;
#pragma unroll
    for (int k = 0; k < PPT; ++k) {
      float dx = __fsub_rn(sx, px[k]);
      float dy = __fsub_rn(sy, py[k]);
      float dz = __fsub_rn(sz, pz[k]);
      float d  = __fadd_rn(__fadd_rn(__fmul_rn(dx, dx), __fmul_rn(dy, dy)),
                           __fmul_rn(dz, dz));
      float c  = fminf(cl[k], d);
      cl[k] = c;
      if (c > bestv) { bestv = c; bestk = k; }
    }
    const int bestidx = base + bestk * TPB + t;

    // --- fused wave reduce: ONE 6-stage u64 DPP chain (bit-exact, r5-r9) ---
    u64 key = ((u64)__float_as_uint(bestv) << 32) |
              ((u64)(unsigned)(65535 - bestidx) << 16);
    key = dppmax_u64<0xB1>(key);
    key = dppmax_u64<0x4E>(key);
    key = dppmax_u64<0x141>(key);
    key = dppmax_u64<0x140>(key);
    key = dppmax_u64<0x142>(key);
    key = dppmax_u64<0x143>(key);

    if (lane == 63) s_wred[wave] = key;
    __syncthreads();  // barrier #1 (HW barrier: r6 proved spins are worse)

    const int p = (it + 1) & 1;            // parity double-buffer
    const unsigned want32 = (unsigned)(it + 1);
    const u64 want = (u64)want32;
    u64* bs = slots + (size_t)(p * BATCHES + b) * PB;

    // --- t0: reduce the 4 wave keys, publish ONE 8-B slot ---
    // Fast mode: plain write-back store (updates/allocates shared-L2 line).
    // Fallback: agent store (write-through to L3; r3-proven).
    if (t == 0) {
      u64 bk = s_wred[0];
#pragma unroll
      for (int w = 1; w < WPB; ++w) {
        u64 o = s_wred[w];
        if (o > bk) bk = o;
      }
      u64 slotval = bk | want;
      if (use_l2) st_plain(bs + r, slotval);
      else
        __hip_atomic_store(bs + r, slotval, __ATOMIC_RELAXED,
                           __HIP_MEMORY_SCOPE_AGENT);
    }
    asm volatile("" ::: "memory");  // keep publish above the poll

    // --- wave 0, lanes 0-15: poll the 16 slots (2 lines, r3 geometry) ---
    if (wave == 0 && lane < PB) {
      const u64* sp = bs + lane;
      u64 sv;
      if (use_l2) {
        // sc0 samples at L2 RTT; every 4th is agent-scope (liveness
        // backstop for the evicted/missed-through case). Exact seq tags
        // make any staleness a harmless mismatch.
        unsigned n = 0;
        for (;;) {
          sv = ((n & 3u) == 3u) ? ld_agent(sp) : ld_sc0(sp);
          if ((sv & 0xFFFFull) == want) break;
          ++n;
        }
      } else {
        do {
          sv = ld_agent(sp);
        } while ((sv & 0xFFFFull) != want);
      }

      // Prefetch this slot's candidate coords; overlapped with the reduce.
      // (Batch coord slice = 786 KB -> L2-resident in fast mode.)
      int ci = 65535 - (int)((sv >> 16) & 0xFFFFull);
      float gx = cb[3 * ci + 0];
      float gy = cb[3 * ci + 1];
      float gz = cb[3 * ci + 2];

      // 16-lane slot reduce: 4 DPP stages within the row (r1/r3-proven).
      u64 m = sv;
      m = dppmax_u64<0xB1>(m);
      m = dppmax_u64<0x4E>(m);
      m = dppmax_u64<0x141>(m);
      m = dppmax_u64<0x140>(m);

      // Winner lane unique (disjoint idx ranges -> unique inv_idx).
      if (sv == m) {
        s_x = gx; s_y = gy; s_z = gz;
        if (r == 0) {
          float* op = out + ((size_t)b * NSAMP + it) * 3;
          op[0] = gx; op[1] = gy; op[2] = gz;
        }
      }
    }
    __syncthreads();  // barrier #2
    sx = s_x; sy = s_y; sz = s_z;
  }
}

extern "C" void kernel_launch(void* const* d_in, const int* in_sizes, int n_in,
                              void* d_out, int out_size, void* d_ws,
                              size_t ws_size, hipStream_t stream) {
  const float* coords = (const float*)d_in[0];  // (16, 65536, 3) fp32
  // d_in[1] (features) unused by the reference output.
  float* out = (float*)d_out;                   // (16, 2048, 3) fp32
  u64* slots = (u64*)d_ws;                      // 4 KiB
  unsigned* xcdtab = (unsigned*)((char*)d_ws + WS_SLOTS_BYTES);  // 1 KiB
  hipMemsetAsync(d_ws, 0, WS_TOTAL_BYTES, stream);
  fps_kernel<<<dim3(BATCHES * PB), dim3(TPB), 0, stream>>>(coords, out, slots,
                                                           xcdtab);
}